// Round 6
// baseline (109.811 us; speedup 1.0000x reference)
//
#include <hip/hip_runtime.h>

#define N_NODES 50000
#define IN_DIM 64
#define OUT_DIM 128
#define N_EDGES 800000
#define LSTRIDE 68

#define NBLK 128                    // partition blocks
#define EPB (N_EDGES / NBLK)        // 6250 edges per block (exact)
#define NBUCK 196                   // ceil(50000/256) buckets of 256 dsts

__device__ __forceinline__ unsigned short f2bf(float f) {
    unsigned u = __float_as_uint(f);
    unsigned r = u + 0x7FFFu + ((u >> 16) & 1u);   // round-to-nearest-even
    return (unsigned short)(r >> 16);
}

// ---------------- A0: per-(block,bucket) histogram + x->bf16 convert ----------------
__global__ __launch_bounds__(256) void bucket_count_cvt(const int* __restrict__ ei,
                                                        const float* __restrict__ x,
                                                        int* __restrict__ cnt_mat,
                                                        unsigned short* __restrict__ xh)
{
    __shared__ int h[NBUCK];
    int t = threadIdx.x, blk = blockIdx.x;
    for (int i = t; i < NBUCK; i += 256) h[i] = 0;
    __syncthreads();
    int s = blk * EPB;
    for (int i = s + t; i < s + EPB; i += 256)
        atomicAdd(&h[ei[N_EDGES + i] >> 8], 1);
    // fused: convert this block's slice of x to bf16 (800000 float4 total / 128 blocks)
    for (int i = t; i < 6250; i += 256) {
        int gi = blk * 6250 + i;
        float4 v = ((const float4*)x)[gi];
        ushort4 o;
        o.x = f2bf(v.x); o.y = f2bf(v.y); o.z = f2bf(v.z); o.w = f2bf(v.w);
        ((ushort4*)xh)[gi] = o;
    }
    __syncthreads();
    for (int b = t; b < NBUCK; b += 256) cnt_mat[b * NBLK + blk] = h[b];
}

// ---------------- scan: one kernel. Each block redundantly computes bucket totals
// + bucket starts in LDS; its 4 waves then scan their cnt_mat rows into cursors.
__global__ __launch_bounds__(256) void rowscan(int* __restrict__ cnt_mat)
{
    __shared__ int tot[NBUCK];
    __shared__ int bst[NBUCK];
    __shared__ int ws[4];
    int t = threadIdx.x, lane = t & 63, wid = t >> 6;
    if (t < NBUCK) {
        const int4* row = (const int4*)(cnt_mat + t * NBLK);
        int sum = 0;
#pragma unroll 8
        for (int i = 0; i < NBLK / 4; ++i) { int4 v = row[i]; sum += v.x + v.y + v.z + v.w; }
        tot[t] = sum;
    }
    __syncthreads();
    int v = (t < NBUCK) ? tot[t] : 0;
    int incl = v;
#pragma unroll
    for (int d = 1; d < 64; d <<= 1) {
        int u = __shfl_up(incl, d, 64);
        if (lane >= d) incl += u;
    }
    if (lane == 63) ws[wid] = incl;
    __syncthreads();
    int woff = 0;
    for (int w = 0; w < wid; ++w) woff += ws[w];
    if (t < NBUCK) bst[t] = woff + incl - v;
    __syncthreads();
    int b = blockIdx.x * 4 + wid;
    if (b >= NBUCK) return;
    int base = bst[b];
#pragma unroll
    for (int c = 0; c < 2; ++c) {
        int idx = c * 64 + lane;
        int cv = cnt_mat[b * NBLK + idx];
        int ic = cv;
#pragma unroll
        for (int d = 1; d < 64; d <<= 1) {
            int u = __shfl_up(ic, d, 64);
            if (lane >= d) ic += u;
        }
        cnt_mat[b * NBLK + idx] = base + ic - cv;
        base += __shfl(ic, 63, 64);
    }
}

// ---------------- A1: partition edges into bucket-contiguous packed ebuf ----------------
// pack = src (16b) | dst_local (8b) << 16
__global__ __launch_bounds__(256) void bucket_place(const int* __restrict__ ei,
                                                    const int* __restrict__ cnt_scan,
                                                    unsigned* __restrict__ ebuf)
{
    __shared__ int cur[NBUCK];
    int t = threadIdx.x, blk = blockIdx.x;
    for (int b = t; b < NBUCK; b += 256) cur[b] = cnt_scan[b * NBLK + blk];
    __syncthreads();
    int s = blk * EPB;
    for (int i = s + t; i < s + EPB; i += 256) {
        int src = ei[i], dst = ei[N_EDGES + i];
        int slot = atomicAdd(&cur[dst >> 8], 1);
        ebuf[slot] = (unsigned)src | ((unsigned)(dst & 255) << 16);
    }
}

// ---------------- B: final CSR within each bucket (1 block per bucket) ----------------
__global__ __launch_bounds__(256) void bucket_bin(const unsigned* __restrict__ ebuf,
                                                  const int* __restrict__ cnt_scan,
                                                  int* __restrict__ srcs,
                                                  int* __restrict__ offs)
{
    __shared__ int h[256];
    __shared__ int ws2[4];
    __shared__ int range_s[2];
    int t = threadIdx.x, b = blockIdx.x;
    int lane = t & 63, wid = t >> 6;
    if (t == 0) {
        range_s[0] = cnt_scan[b * NBLK];
        range_s[1] = (b < NBUCK - 1) ? cnt_scan[(b + 1) * NBLK] : N_EDGES;
    }
    h[t] = 0;
    __syncthreads();
    int bs = range_s[0], be = range_s[1];
    for (int i = bs + t; i < be; i += 256)
        atomicAdd(&h[(ebuf[i] >> 16) & 255], 1);
    __syncthreads();
    int v = h[t];
    int incl = v;
#pragma unroll
    for (int d = 1; d < 64; d <<= 1) {
        int u = __shfl_up(incl, d, 64);
        if (lane >= d) incl += u;
    }
    if (lane == 63) ws2[wid] = incl;
    __syncthreads();
    int woff = 0;
    for (int w = 0; w < wid; ++w) woff += ws2[w];
    incl += woff;
    int ex = incl - v;
    h[t] = bs + ex;
    int node = b * 256 + t;
    if (node < N_NODES) offs[node] = bs + incl;
    __syncthreads();
    for (int i = bs + t; i < be; i += 256) {
        unsigned p = ebuf[i];
        int pos = atomicAdd(&h[(p >> 16) & 255], 1);
        srcs[pos] = (int)(p & 0xFFFFu);
    }
}

// ---------------- gather + mean from bf16 x (wave per node, 2 edges per load) ----------------
// lane < 32: even-slot edges, lane >= 32: odd-slot edges; each lane covers feature
// pair (2*fl, 2*fl+1) as one 4B load. 4 edges (2 loads) in flight per iteration.
__global__ __launch_bounds__(256) void gather_bf16(const unsigned short* __restrict__ xh,
                                                   const int* __restrict__ offs,
                                                   const int* __restrict__ srcs,
                                                   float* __restrict__ mean)
{
    int n = (blockIdx.x * 256 + threadIdx.x) >> 6;
    int lane = threadIdx.x & 63;
    if (n >= N_NODES) return;
    int half = lane >> 5;
    int fl = lane & 31;
    int end = offs[n];
    int start = n ? offs[n - 1] : 0;
    float a0 = 0.f, a1 = 0.f;
    for (int j = start; j < end; j += 64) {
        int m = end - j; if (m > 64) m = 64;
        int sv = (lane < m) ? srcs[j + lane] : 0;
        for (int k = 0; k < m; k += 4) {
            int sA = __shfl(sv, k, 64),     sB = __shfl(sv, k + 1, 64);
            int sC = __shfl(sv, k + 2, 64), sD = __shfl(sv, k + 3, 64);
            int s0 = half ? sB : sA;
            int s1 = half ? sD : sC;
            unsigned u0 = *(const unsigned*)(xh + (size_t)s0 * IN_DIM + fl * 2);
            unsigned u1 = *(const unsigned*)(xh + (size_t)s1 * IN_DIM + fl * 2);
            bool v0 = (k + half) < m;
            bool v1 = (k + 2 + half) < m;
            float f00 = __uint_as_float(u0 << 16);
            float f01 = __uint_as_float(u0 & 0xFFFF0000u);
            float f10 = __uint_as_float(u1 << 16);
            float f11 = __uint_as_float(u1 & 0xFFFF0000u);
            a0 += v0 ? f00 : 0.f;  a1 += v0 ? f01 : 0.f;
            a0 += v1 ? f10 : 0.f;  a1 += v1 ? f11 : 0.f;
        }
    }
    a0 += __shfl_xor(a0, 32, 64);
    a1 += __shfl_xor(a1, 32, 64);
    int deg = end - start;
    float inv = deg ? 1.0f / (float)deg : 0.0f;
    if (lane < 32)
        *(float2*)(mean + (size_t)n * IN_DIM + fl * 2) = make_float2(a0 * inv, a1 * inv);
}

// ---------------- register-tiled linear: 128-node x 128-out tile, 8x8/thread ----------------
__global__ __launch_bounds__(256) void sage_linear4(
    const float* __restrict__ x, const float* __restrict__ mean,
    const float* __restrict__ Wl, const float* __restrict__ bl,
    const float* __restrict__ Wr, float* __restrict__ out)
{
    __shared__ float R[128 * LSTRIDE];
    __shared__ float Wt[128 * LSTRIDE];

    const int t = threadIdx.x;
    const int tc = t & 15;          // out group: o = tc + 16j
    const int tr = t >> 4;          // node group: n_loc = tr + 16i
    const int nbase = blockIdx.x * 128;

    float acc[8][8];
#pragma unroll
    for (int i = 0; i < 8; ++i)
#pragma unroll
        for (int j = 0; j < 8; ++j) acc[i][j] = 0.f;

#pragma unroll
    for (int ph = 0; ph < 2; ++ph) {
        const float* rowsrc = ph ? mean : x;
        const float* wsrc   = ph ? Wl : Wr;
#pragma unroll
        for (int it = 0; it < 8; ++it) {
            int flat = it * 256 + t;          // float4 index within 128x16
            int nd = flat >> 4, k4 = flat & 15;
            int gn = nbase + nd;
            float4 rv = make_float4(0.f, 0.f, 0.f, 0.f);
            if (gn < N_NODES) rv = *(const float4*)(rowsrc + (size_t)gn * IN_DIM + k4 * 4);
            *(float4*)(R + nd * LSTRIDE + k4 * 4) = rv;
            float4 wv = *(const float4*)(wsrc + (size_t)nd * IN_DIM + k4 * 4);
            *(float4*)(Wt + nd * LSTRIDE + k4 * 4) = wv;
        }
        __syncthreads();
#pragma unroll 2
        for (int k = 0; k < 64; k += 4) {
            float4 r[8], w[8];
#pragma unroll
            for (int i = 0; i < 8; ++i) r[i] = *(const float4*)(R + (tr + 16 * i) * LSTRIDE + k);
#pragma unroll
            for (int j = 0; j < 8; ++j) w[j] = *(const float4*)(Wt + (tc + 16 * j) * LSTRIDE + k);
#pragma unroll
            for (int i = 0; i < 8; ++i)
#pragma unroll
                for (int j = 0; j < 8; ++j) {
                    acc[i][j] = fmaf(r[i].x, w[j].x, acc[i][j]);
                    acc[i][j] = fmaf(r[i].y, w[j].y, acc[i][j]);
                    acc[i][j] = fmaf(r[i].z, w[j].z, acc[i][j]);
                    acc[i][j] = fmaf(r[i].w, w[j].w, acc[i][j]);
                }
        }
        __syncthreads();
    }

    float bj[8];
#pragma unroll
    for (int j = 0; j < 8; ++j) bj[j] = bl[tc + 16 * j];

#pragma unroll
    for (int i = 0; i < 8; ++i) {
        int n = nbase + tr + 16 * i;
        if (n < N_NODES) {
#pragma unroll
            for (int j = 0; j < 8; ++j)
                out[(size_t)n * OUT_DIM + tc + 16 * j] = acc[i][j] + bj[j];
        }
    }
}

extern "C" void kernel_launch(void* const* d_in, const int* in_sizes, int n_in,
                              void* d_out, int out_size, void* d_ws, size_t ws_size,
                              hipStream_t stream) {
    const float* x  = (const float*)d_in[0];
    const int*   ei = (const int*)d_in[1];
    const float* Wl = (const float*)d_in[2];
    const float* bl = (const float*)d_in[3];
    const float* Wr = (const float*)d_in[4];
    float* out = (float*)d_out;

    // ws layout:
    //   srcs[800000 int] | offs[50000 int] | xh[3.2M ushort] | X region (12.8 MB):
    //     X as {cnt_mat[25088 int] in first 128KB, ebuf[800000 uint] after}
    //     X as mean[3.2M float]  (cnt_mat/ebuf dead before gather writes mean)
    int*            srcs = (int*)d_ws;
    int*            offs = srcs + N_EDGES;
    unsigned short* xh   = (unsigned short*)(offs + N_NODES);
    char*           X    = (char*)(xh + (size_t)N_NODES * IN_DIM);
    int*            cnt_mat = (int*)X;
    unsigned*       ebuf    = (unsigned*)(X + 131072);
    float*          mean    = (float*)X;

    bucket_count_cvt<<<NBLK, 256, 0, stream>>>(ei, x, cnt_mat, xh);
    rowscan<<<(NBUCK + 3) / 4, 256, 0, stream>>>(cnt_mat);
    bucket_place<<<NBLK, 256, 0, stream>>>(ei, cnt_mat, ebuf);
    bucket_bin<<<NBUCK, 256, 0, stream>>>(ebuf, cnt_mat, srcs, offs);

    int gb = (N_NODES * 64 + 255) / 256;            // 12500
    gather_bf16<<<gb, 256, 0, stream>>>(xh, offs, srcs, mean);

    int ntile = (N_NODES + 127) / 128;              // 391
    sage_linear4<<<ntile, 256, 0, stream>>>(x, mean, Wl, bl, Wr, out);
}

// Round 7
// 80.816 us; speedup vs baseline: 1.3588x; 1.3588x over previous
//
#include <hip/hip_runtime.h>

#define N_NODES 50000
#define IN_DIM 64
#define OUT_DIM 128
#define N_EDGES 800000

#define NBLK 128                    // partition blocks
#define EPB (N_EDGES / NBLK)        // 6250 edges per block (exact)
#define NBUCK 196                   // ceil(50000/256) buckets of 256 dsts
#define NSTRIP (N_NODES / 16)       // 3125 16-node strips (exact)
#define WLDS 136                    // padded bf16 row stride: bank step 4 -> 2-way (free)

typedef __attribute__((ext_vector_type(8))) short bf16x8;
typedef __attribute__((ext_vector_type(4))) float f32x4;

__device__ __forceinline__ unsigned short f2bf(float f) {
    unsigned u = __float_as_uint(f);
    unsigned r = u + 0x7FFFu + ((u >> 16) & 1u);   // round-to-nearest-even
    return (unsigned short)(r >> 16);
}

// ---------------- A0: per-(block,bucket) histogram + x->bf16 + W2->bf16 ----------------
__global__ __launch_bounds__(256) void bucket_count_cvt(const int* __restrict__ ei,
                                                        const float* __restrict__ x,
                                                        const float* __restrict__ Wl,
                                                        const float* __restrict__ Wr,
                                                        int* __restrict__ cnt_mat,
                                                        unsigned short* __restrict__ xh,
                                                        unsigned short* __restrict__ w2h)
{
    __shared__ int h[NBUCK];
    int t = threadIdx.x, blk = blockIdx.x;
    for (int i = t; i < NBUCK; i += 256) h[i] = 0;
    __syncthreads();
    int s = blk * EPB;
    for (int i = s + t; i < s + EPB; i += 256)
        atomicAdd(&h[ei[N_EDGES + i] >> 8], 1);
    // fused: convert this block's slice of x to bf16
    for (int i = t; i < 6250; i += 256) {
        int gi = blk * 6250 + i;
        float4 v = ((const float4*)x)[gi];
        ushort4 o;
        o.x = f2bf(v.x); o.y = f2bf(v.y); o.z = f2bf(v.z); o.w = f2bf(v.w);
        ((ushort4*)xh)[gi] = o;
    }
    // fused: W2h[o] = [Wr[o] | Wl[o]] in bf16 (block blk handles o=blk)
    if (t < 64) {
        w2h[blk * 128 + t]      = f2bf(Wr[blk * 64 + t]);
        w2h[blk * 128 + 64 + t] = f2bf(Wl[blk * 64 + t]);
    }
    __syncthreads();
    for (int b = t; b < NBUCK; b += 256) cnt_mat[b * NBLK + blk] = h[b];
}

// ---------------- scan: each block redundantly computes bucket starts in LDS;
// its 4 waves then scan their cnt_mat rows into per-(bucket,block) cursors.
__global__ __launch_bounds__(256) void rowscan(int* __restrict__ cnt_mat)
{
    __shared__ int tot[NBUCK];
    __shared__ int bst[NBUCK];
    __shared__ int ws[4];
    int t = threadIdx.x, lane = t & 63, wid = t >> 6;
    if (t < NBUCK) {
        const int4* row = (const int4*)(cnt_mat + t * NBLK);
        int sum = 0;
#pragma unroll 8
        for (int i = 0; i < NBLK / 4; ++i) { int4 v = row[i]; sum += v.x + v.y + v.z + v.w; }
        tot[t] = sum;
    }
    __syncthreads();
    int v = (t < NBUCK) ? tot[t] : 0;
    int incl = v;
#pragma unroll
    for (int d = 1; d < 64; d <<= 1) {
        int u = __shfl_up(incl, d, 64);
        if (lane >= d) incl += u;
    }
    if (lane == 63) ws[wid] = incl;
    __syncthreads();
    int woff = 0;
    for (int w = 0; w < wid; ++w) woff += ws[w];
    if (t < NBUCK) bst[t] = woff + incl - v;
    __syncthreads();
    int b = blockIdx.x * 4 + wid;
    if (b >= NBUCK) return;
    int base = bst[b];
#pragma unroll
    for (int c = 0; c < 2; ++c) {
        int idx = c * 64 + lane;
        int cv = cnt_mat[b * NBLK + idx];
        int ic = cv;
#pragma unroll
        for (int d = 1; d < 64; d <<= 1) {
            int u = __shfl_up(ic, d, 64);
            if (lane >= d) ic += u;
        }
        cnt_mat[b * NBLK + idx] = base + ic - cv;
        base += __shfl(ic, 63, 64);
    }
}

// ---------------- A1: partition edges into bucket-contiguous packed ebuf ----------------
// pack = src (16b) | dst_local (8b) << 16   (src < 50000 < 65536)
__global__ __launch_bounds__(256) void bucket_place(const int* __restrict__ ei,
                                                    const int* __restrict__ cnt_scan,
                                                    unsigned* __restrict__ ebuf)
{
    __shared__ int cur[NBUCK];
    int t = threadIdx.x, blk = blockIdx.x;
    for (int b = t; b < NBUCK; b += 256) cur[b] = cnt_scan[b * NBLK + blk];
    __syncthreads();
    int s = blk * EPB;
    for (int i = s + t; i < s + EPB; i += 256) {
        int src = ei[i], dst = ei[N_EDGES + i];
        int slot = atomicAdd(&cur[dst >> 8], 1);
        ebuf[slot] = (unsigned)src | ((unsigned)(dst & 255) << 16);
    }
}

// ---------------- B: final CSR within each bucket (1 block per bucket) ----------------
__global__ __launch_bounds__(256) void bucket_bin(const unsigned* __restrict__ ebuf,
                                                  const int* __restrict__ cnt_scan,
                                                  unsigned short* __restrict__ srcs,
                                                  int* __restrict__ offs)
{
    __shared__ int h[256];
    __shared__ int ws2[4];
    __shared__ int range_s[2];
    int t = threadIdx.x, b = blockIdx.x;
    int lane = t & 63, wid = t >> 6;
    if (t == 0) {
        range_s[0] = cnt_scan[b * NBLK];
        range_s[1] = (b < NBUCK - 1) ? cnt_scan[(b + 1) * NBLK] : N_EDGES;
    }
    h[t] = 0;
    __syncthreads();
    int bs = range_s[0], be = range_s[1];
    for (int i = bs + t; i < be; i += 256)
        atomicAdd(&h[(ebuf[i] >> 16) & 255], 1);
    __syncthreads();
    int v = h[t];
    int incl = v;
#pragma unroll
    for (int d = 1; d < 64; d <<= 1) {
        int u = __shfl_up(incl, d, 64);
        if (lane >= d) incl += u;
    }
    if (lane == 63) ws2[wid] = incl;
    __syncthreads();
    int woff = 0;
    for (int w = 0; w < wid; ++w) woff += ws2[w];
    incl += woff;
    int ex = incl - v;
    h[t] = bs + ex;
    int node = b * 256 + t;
    if (node < N_NODES) offs[node] = bs + incl;
    __syncthreads();
    for (int i = bs + t; i < be; i += 256) {
        unsigned p = ebuf[i];
        int pos = atomicAdd(&h[(p >> 16) & 255], 1);
        srcs[pos] = (unsigned short)(p & 0xFFFFu);
    }
}

// ---------------- gather + mean (bf16 in, bf16 out; wave per node; 8-edge unroll) ----------------
// lane half h in {0,1}; lane covers feature pair (2*fl, 2*fl+1); 4 loads in flight.
__global__ __launch_bounds__(256) void gather_bf16(const unsigned short* __restrict__ xh,
                                                   const int* __restrict__ offs,
                                                   const unsigned short* __restrict__ srcs,
                                                   unsigned short* __restrict__ meanh)
{
    int n = (blockIdx.x * 256 + threadIdx.x) >> 6;
    int lane = threadIdx.x & 63;
    if (n >= N_NODES) return;
    int half = lane >> 5;
    int fl = lane & 31;
    int end = offs[n];
    int start = n ? offs[n - 1] : 0;
    float a0 = 0.f, a1 = 0.f;
    for (int j = start; j < end; j += 64) {
        int m = end - j; if (m > 64) m = 64;
        int sv = (lane < m) ? (int)srcs[j + lane] : 0;
        for (int k = 0; k < m; k += 8) {
            int e0 = k + half, e1 = k + 2 + half, e2 = k + 4 + half, e3 = k + 6 + half;
            int s0 = __shfl(sv, e0, 64);
            int s1 = __shfl(sv, e1, 64);
            int s2 = __shfl(sv, e2, 64);
            int s3 = __shfl(sv, e3, 64);
            unsigned u0 = *(const unsigned*)(xh + (size_t)s0 * IN_DIM + fl * 2);
            unsigned u1 = *(const unsigned*)(xh + (size_t)s1 * IN_DIM + fl * 2);
            unsigned u2 = *(const unsigned*)(xh + (size_t)s2 * IN_DIM + fl * 2);
            unsigned u3 = *(const unsigned*)(xh + (size_t)s3 * IN_DIM + fl * 2);
            a0 += (e0 < m) ? __uint_as_float(u0 << 16) : 0.f;
            a1 += (e0 < m) ? __uint_as_float(u0 & 0xFFFF0000u) : 0.f;
            a0 += (e1 < m) ? __uint_as_float(u1 << 16) : 0.f;
            a1 += (e1 < m) ? __uint_as_float(u1 & 0xFFFF0000u) : 0.f;
            a0 += (e2 < m) ? __uint_as_float(u2 << 16) : 0.f;
            a1 += (e2 < m) ? __uint_as_float(u2 & 0xFFFF0000u) : 0.f;
            a0 += (e3 < m) ? __uint_as_float(u3 << 16) : 0.f;
            a1 += (e3 < m) ? __uint_as_float(u3 & 0xFFFF0000u) : 0.f;
        }
    }
    a0 += __shfl_xor(a0, 32, 64);
    a1 += __shfl_xor(a1, 32, 64);
    int deg = end - start;
    float inv = deg ? 1.0f / (float)deg : 0.0f;
    if (lane < 32) {
        unsigned mh = (unsigned)f2bf(a0 * inv) | ((unsigned)f2bf(a1 * inv) << 16);
        *(unsigned*)(meanh + (size_t)n * IN_DIM + fl * 2) = mh;
    }
}

// ---------------- MFMA linear: out = [xh|meanh] @ W2h^T + b ----------------
// One wave per 16-node strip, all 128 outs: 8 out-tiles x 4 k-steps of
// mfma_f32_16x16x32_bf16. A frag: lane holds z[nbase+(l&15)][kk + (l>>4)*8 ..+7].
// B frag: lane holds W2[ot*16+(l&15)][kk + (l>>4)*8 ..+7] from padded LDS.
// D: col=lane&15 (out), row=(lane>>4)*4+reg (node)  [guide-verified mapping].
__global__ __launch_bounds__(256) void sage_mfma(
    const unsigned short* __restrict__ xh, const unsigned short* __restrict__ meanh,
    const unsigned short* __restrict__ w2h, const float* __restrict__ bl,
    float* __restrict__ out)
{
    __shared__ unsigned short wlds[128 * WLDS];   // 34.8 KB
    int t = threadIdx.x;
#pragma unroll
    for (int c = 0; c < 8; ++c) {
        int idx = c * 256 + t;          // 2048 chunks of 8 bf16
        int o = idx >> 4, kc = idx & 15;
        bf16x8 v = *(const bf16x8*)(w2h + o * 128 + kc * 8);
        *(bf16x8*)(&wlds[o * WLDS + kc * 8]) = v;
    }
    __syncthreads();

    int wid = t >> 6, lane = t & 63;
    int strip = blockIdx.x * 4 + wid;
    if (strip >= NSTRIP) return;
    int nbase = strip * 16;
    int row = lane & 15, q = lane >> 4;

    const unsigned short* xrow = xh    + (size_t)(nbase + row) * IN_DIM + q * 8;
    const unsigned short* mrow = meanh + (size_t)(nbase + row) * IN_DIM + q * 8;
    bf16x8 a[4];
    a[0] = *(const bf16x8*)(xrow);
    a[1] = *(const bf16x8*)(xrow + 32);
    a[2] = *(const bf16x8*)(mrow);
    a[3] = *(const bf16x8*)(mrow + 32);

    f32x4 acc[8];
#pragma unroll
    for (int ot = 0; ot < 8; ++ot) acc[ot] = (f32x4){0.f, 0.f, 0.f, 0.f};

#pragma unroll
    for (int ot = 0; ot < 8; ++ot) {
        const unsigned short* wb = &wlds[(ot * 16 + row) * WLDS + q * 8];
#pragma unroll
        for (int s = 0; s < 4; ++s) {
            bf16x8 b = *(const bf16x8*)(wb + s * 32);
            acc[ot] = __builtin_amdgcn_mfma_f32_16x16x32_bf16(a[s], b, acc[ot], 0, 0, 0);
        }
    }

#pragma unroll
    for (int ot = 0; ot < 8; ++ot) {
        float bias = bl[ot * 16 + row];
#pragma unroll
        for (int r = 0; r < 4; ++r) {
            int n = nbase + q * 4 + r;
            out[(size_t)n * OUT_DIM + ot * 16 + row] = acc[ot][r] + bias;
        }
    }
}

extern "C" void kernel_launch(void* const* d_in, const int* in_sizes, int n_in,
                              void* d_out, int out_size, void* d_ws, size_t ws_size,
                              hipStream_t stream) {
    const float* x  = (const float*)d_in[0];
    const int*   ei = (const int*)d_in[1];
    const float* Wl = (const float*)d_in[2];
    const float* bl = (const float*)d_in[3];
    const float* Wr = (const float*)d_in[4];
    float* out = (float*)d_out;

    // ws layout (~17.9 MB, no aliasing):
    int*            cnt_mat = (int*)d_ws;                               // 25088 ints
    unsigned*       ebuf    = (unsigned*)(cnt_mat + NBUCK * NBLK);      // 800000 uints
    int*            offs    = (int*)(ebuf + N_EDGES);                   // 50000 ints
    unsigned short* xh      = (unsigned short*)(offs + N_NODES);        // 3.2M bf16
    unsigned short* meanh   = xh + (size_t)N_NODES * IN_DIM;            // 3.2M bf16
    unsigned short* w2h     = meanh + (size_t)N_NODES * IN_DIM;         // 16384 bf16
    unsigned short* srcs    = w2h + 128 * 128;                          // 800000 ushort

    bucket_count_cvt<<<NBLK, 256, 0, stream>>>(ei, x, Wl, Wr, cnt_mat, xh, w2h);
    rowscan<<<(NBUCK + 3) / 4, 256, 0, stream>>>(cnt_mat);
    bucket_place<<<NBLK, 256, 0, stream>>>(ei, cnt_mat, ebuf);
    bucket_bin<<<NBUCK, 256, 0, stream>>>(ebuf, cnt_mat, srcs, offs);

    int gb = (N_NODES * 64 + 255) / 256;            // 12500
    gather_bf16<<<gb, 256, 0, stream>>>(xh, offs, srcs, meanh);

    int mb = (NSTRIP + 3) / 4;                      // 782
    sage_mfma<<<mb, 256, 0, stream>>>(xh, meanh, w2h, bl, out);
}